// Round 6
// baseline (2670.531 us; speedup 1.0000x reference)
//
#include <hip/hip_runtime.h>
#include <cmath>

#define NL 8
#define NR 8
#define DIM 768
#define LTOK 512
#define RTOK 512
#define EDIM 12288   // (NL+NR)*DIM
#define KST 32       // K per pipeline stage

typedef unsigned short u16;
typedef __bf16 bf16x8 __attribute__((ext_vector_type(8)));
typedef float  f32x16 __attribute__((ext_vector_type(16)));

#define WARR 589824          // 768*768 elements per split array
// frag-major layout for W (per array): idx(k,d) = ((k>>3)*768 + d)*8 + (k&7)

// RNE split of f32 into bf16 hi + bf16 lo (x ~= hi + lo; residual exact in f32)
__device__ __forceinline__ void splitbf(float c, u16& hi, u16& lo) {
    __bf16 h = (__bf16)c;
    __bf16 l = (__bf16)(c - (float)h);
    hi = __builtin_bit_cast(u16, h);
    lo = __builtin_bit_cast(u16, l);
}

__device__ __forceinline__ void gll16(const void* gsrc, void* lds) {
    __builtin_amdgcn_global_load_lds(
        (const __attribute__((address_space(1))) unsigned int*)gsrc,
        (__attribute__((address_space(3))) unsigned int*)lds, 16, 0, 0);
}

// ---------------------------------------------------------------------------
// Kernel 0: pre-split token-matching weights into bf16 hi/lo, frag-major.
// out: [wn_hi | wn_lo | wg_hi | wg_lo], each WARR u16.
// ---------------------------------------------------------------------------
__global__ __launch_bounds__(256) void wsplit_kernel(
    const float* __restrict__ Wn, const float* __restrict__ Wg, u16* __restrict__ out)
{
    const int gid = blockIdx.x * 256 + threadIdx.x;   // 768 d x 96 kg = 73728
    const int d  = gid % DIM;
    const int kg = gid / DIM;
    u16 hn[8], ln[8], hg[8], lg2[8];
#pragma unroll
    for (int e = 0; e < 8; ++e) {
        splitbf(Wn[(size_t)(kg * 8 + e) * DIM + d], hn[e], ln[e]);
        splitbf(Wg[(size_t)(kg * 8 + e) * DIM + d], hg[e], lg2[e]);
    }
    const size_t fo = ((size_t)kg * DIM + d) * 8;
    *(uint4*)&out[fo]            = *(uint4*)hn;
    *(uint4*)&out[WARR + fo]     = *(uint4*)ln;
    *(uint4*)&out[2 * WARR + fo] = *(uint4*)hg;
    *(uint4*)&out[3 * WARR + fo] = *(uint4*)lg2;
}

// ---------------------------------------------------------------------------
// Kernel 1: token-matching scores via bf16x3 split MFMA (32x32x16).
// v3: nested (sweep x kstage) loops, pointer-increment addressing (compile-
// time strides), epilogue hoisted out of the hot body. Math identical to v2.
// ---------------------------------------------------------------------------
__global__ __launch_bounds__(256, 2) void scores_kernel(
    const float* __restrict__ Lg, const float* __restrict__ Rg,
    const u16* __restrict__ wfrag,
    const float* __restrict__ bn, const float* __restrict__ bg,
    const float* __restrict__ Wl,
    float* __restrict__ scores)
{
    __shared__ u16   wLDS[2][8192];     // [buf][arr4][kg4][d64][e8]  16KB/buf
    __shared__ float lT[2][64][34];     // [buf][i-row][k32 + pad2]
    __shared__ float rT[4][768];        // [j-row][full K]

    const int t    = threadIdx.x;
    const int lane = t & 63;
    const int wid  = t >> 6;
    const int l31  = lane & 31;
    const int kh   = lane >> 5;
    const int i0   = blockIdx.x * 64;
    const int j0   = blockIdx.y * 4;
    const int j    = j0 + wid;

    const int rowS = t >> 2;            // lT staging: row per thread
    const int cS   = (t & 3) * 8;       // 8 floats per thread

    // pointer strides (u16 elements)
    const ptrdiff_t WSTEP = (ptrdiff_t)4 * DIM * 8;          //  +24576  (kgb += 4)
    const ptrdiff_t WROLL = (ptrdiff_t)(64 - 92 * DIM) * 8;  // -564736  (kgb 92->0, dg += 64)

    // ---- prologue: rT full-K + stage 0 into buf 0 ----
#pragma unroll
    for (int it = 0; it < 3; ++it) {
        int idx = it * 256 + t;                 // float4 idx 0..767
        int row = idx / 192;
        int c4  = (idx - row * 192) * 4;
        *(float4*)&rT[row][c4] = *(const float4*)(Rg + (size_t)(j0 + row) * DIM + c4);
    }

    // W chunk pointers: chunk = it*4+wid  ->  arr = it, kg = wid
    const u16* wp[4];
#pragma unroll
    for (int it = 0; it < 4; ++it)
        wp[it] = wfrag + (size_t)it * WARR + ((size_t)wid * DIM + lane) * 8;
    const float* ap = Lg + (size_t)(i0 + rowS) * DIM + cS;

#pragma unroll
    for (int it = 0; it < 4; ++it)
        gll16(wp[it], &wLDS[0][(it * 4 + wid) * 512]);
    {
        float4 a0 = *(const float4*)ap;
        float4 a1 = *(const float4*)(ap + 4);
        float* dst = &lT[0][rowS][cS];
        *(float2*)(dst + 0) = make_float2(a0.x, a0.y);
        *(float2*)(dst + 2) = make_float2(a0.z, a0.w);
        *(float2*)(dst + 4) = make_float2(a1.x, a1.y);
        *(float2*)(dst + 6) = make_float2(a1.z, a1.w);
    }
    // advance to stage 1 (kgb=4, k0=32)
#pragma unroll
    for (int it = 0; it < 4; ++it) wp[it] += WSTEP;
    ap += KST;
    __syncthreads();

    float sacc[2][16];
#pragma unroll
    for (int tile = 0; tile < 2; ++tile)
#pragma unroll
        for (int r = 0; r < 16; ++r) sacc[tile][r] = 0.f;

    int buf = 0;
    for (int sweep = 0; sweep < 12; ++sweep) {
        const int dg = sweep * 64;

        f32x16 acc[2][2][2];                    // [tile][mat][nd]
#pragma unroll
        for (int tile = 0; tile < 2; ++tile)
#pragma unroll
            for (int mat = 0; mat < 2; ++mat)
#pragma unroll
                for (int nd = 0; nd < 2; ++nd)
#pragma unroll
                    for (int r = 0; r < 16; ++r) acc[tile][mat][nd][r] = 0.f;

        for (int ks = 0; ks < 24; ++ks) {
            const bool pref = !(sweep == 11 && ks == 23);

            float4 a0, a1;
            if (pref) {
                // issue next-stage loads: W direct-to-LDS, lT to regs
#pragma unroll
                for (int it = 0; it < 4; ++it)
                    gll16(wp[it], &wLDS[buf ^ 1][(it * 4 + wid) * 512]);
                a0 = *(const float4*)ap;
                a1 = *(const float4*)(ap + 4);
                // advance pointers to the stage after the one just issued
                if (ks == 22) {
#pragma unroll
                    for (int it = 0; it < 4; ++it) wp[it] += WROLL;
                    ap -= 736;
                } else {
#pragma unroll
                    for (int it = 0; it < 4; ++it) wp[it] += WSTEP;
                    ap += KST;
                }
            }

            // ---- compute current stage from buf ----
            {
                const float* rrow = &rT[wid][ks * KST + kh * 8];
                const u16* wb = &wLDS[buf][0];
#pragma unroll
                for (int kk = 0; kk < 2; ++kk) {
                    float rv[8];
#pragma unroll
                    for (int e = 0; e < 8; e += 2) {
                        float2 p = *(const float2*)(rrow + kk * 16 + e);
                        rv[e] = p.x; rv[e + 1] = p.y;
                    }
                    bf16x8 ah[2], al[2];
#pragma unroll
                    for (int tile = 0; tile < 2; ++tile) {
                        const float* lrow = &lT[buf][tile * 32 + l31][kk * 16 + kh * 8];
#pragma unroll
                        for (int e = 0; e < 8; e += 2) {
                            float2 lp = *(const float2*)(lrow + e);
                            float c0 = fabsf(lp.x - rv[e]);
                            float c1 = fabsf(lp.y - rv[e + 1]);
                            __bf16 h0 = (__bf16)c0, h1 = (__bf16)c1;
                            ah[tile][e]     = h0;
                            ah[tile][e + 1] = h1;
                            al[tile][e]     = (__bf16)(c0 - (float)h0);
                            al[tile][e + 1] = (__bf16)(c1 - (float)h1);
                        }
                    }
#pragma unroll
                    for (int mat = 0; mat < 2; ++mat)
#pragma unroll
                        for (int nd = 0; nd < 2; ++nd) {
                            const int base = (mat * 2) * 2048 + (kk * 2 + kh) * 512
                                           + (nd * 32 + l31) * 8;
                            bf16x8 whi = *(const bf16x8*)&wb[base];
                            bf16x8 wlo = *(const bf16x8*)&wb[base + 2048];
#pragma unroll
                            for (int tile = 0; tile < 2; ++tile) {
                                acc[tile][mat][nd] = __builtin_amdgcn_mfma_f32_32x32x16_bf16(
                                    ah[tile], whi, acc[tile][mat][nd], 0, 0, 0);
                                acc[tile][mat][nd] = __builtin_amdgcn_mfma_f32_32x32x16_bf16(
                                    al[tile], whi, acc[tile][mat][nd], 0, 0, 0);
                                acc[tile][mat][nd] = __builtin_amdgcn_mfma_f32_32x32x16_bf16(
                                    ah[tile], wlo, acc[tile][mat][nd], 0, 0, 0);
                            }
                        }
                }
            }

            if (pref) {
                // late write of prefetched lT regs (vmcnt ordered by data dep)
                float* dst = &lT[buf ^ 1][rowS][cS];
                *(float2*)(dst + 0) = make_float2(a0.x, a0.y);
                *(float2*)(dst + 2) = make_float2(a0.z, a0.w);
                *(float2*)(dst + 4) = make_float2(a1.x, a1.y);
                *(float2*)(dst + 6) = make_float2(a1.z, a1.w);
            }

            if (ks == 23) {
                // sweep epilogue: nonlinearity + score accum for d in [dg,dg+64)
                // C layout (32x32): col(d) = lane&31, row(i) = (reg&3)+8*(reg>>2)+4*kh
#pragma unroll
                for (int nd = 0; nd < 2; ++nd) {
                    const int dd = dg + nd * 32 + l31;
                    const float bnv = bn[dd], bgv = bg[dd], wlv = Wl[dd];
                    const float rvv = Rg[(size_t)j * DIM + dd];
#pragma unroll
                    for (int tile = 0; tile < 2; ++tile)
#pragma unroll
                        for (int r = 0; r < 16; ++r) {
                            const int m = (r & 3) + 8 * (r >> 2) + 4 * kh;
                            const int i = i0 + tile * 32 + m;
                            float h  = fmaxf(acc[tile][0][nd][r] + bnv, 0.f);
                            float g  = 1.f / (1.f + __expf(-(acc[tile][1][nd][r] + bgv)));
                            float cc = fabsf(Lg[(size_t)i * DIM + dd] - rvv);
                            sacc[tile][r] = fmaf(wlv, fmaf(g, h - cc, cc), sacc[tile][r]);
                        }
                }
            }

            __syncthreads();
            buf ^= 1;
        }
    }

    // reduce sacc over the 32 lanes of each half (d direction), write scores
#pragma unroll
    for (int tile = 0; tile < 2; ++tile)
#pragma unroll
        for (int r = 0; r < 16; ++r) {
            float v = sacc[tile][r];
            v += __shfl_xor(v, 1);  v += __shfl_xor(v, 2);
            v += __shfl_xor(v, 4);  v += __shfl_xor(v, 8);
            v += __shfl_xor(v, 16);
            if (l31 == 0) {
                const int m = (r & 3) + 8 * (r >> 2) + 4 * kh;
                scores[(size_t)(i0 + tile * 32 + m) * RTOK + j] = v;
            }
        }
}

// ---------------------------------------------------------------------------
// Kernel 2: argmax per row (left) and per column (right); first-occurrence ties.
// ---------------------------------------------------------------------------
__global__ __launch_bounds__(64) void argmax_kernel(
    const float* __restrict__ scores, int* __restrict__ idxL, int* __restrict__ idxR)
{
    const int b = blockIdx.x;          // 0..511 rows, 512..1023 cols
    const int t = threadIdx.x;
    const bool isRow = (b < LTOK);
    const int  n = b & (LTOK - 1);

    float best = -INFINITY;
    int   bidx = 0x7fffffff;
    for (int s = t; s < 512; s += 64) {
        float v = isRow ? scores[n * RTOK + s] : scores[s * RTOK + n];
        if (v > best) { best = v; bidx = s; }
    }
#pragma unroll
    for (int off = 32; off; off >>= 1) {
        float ob = __shfl_down(best, off);
        int   oi = __shfl_down(bidx, off);
        if (ob > best || (ob == best && oi < bidx)) { best = ob; bidx = oi; }
    }
    if (t == 0) (isRow ? idxL : idxR)[n] = bidx;
}

// ---------------------------------------------------------------------------
// Kernel 3: gather chosen cmp rows.
// ---------------------------------------------------------------------------
__global__ __launch_bounds__(256) void build_cmp_kernel(
    const float* __restrict__ Lg, const float* __restrict__ Rg,
    const int* __restrict__ idxL, const int* __restrict__ idxR,
    float* __restrict__ lcmp, float* __restrict__ rcmp)
{
    const int b = blockIdx.x;
    const int t = threadIdx.x;
    if (b < LTOK) {
        const float* a = Lg + b * DIM;
        const float* c = Rg + idxL[b] * DIM;
        for (int d = t; d < DIM; d += 256) lcmp[b * DIM + d] = fabsf(a[d] - c[d]);
    } else {
        const int jj = b - LTOK;
        const float* a = Rg + jj * DIM;
        const float* c = Lg + idxR[jj] * DIM;
        for (int d = t; d < DIM; d += 256) rcmp[jj * DIM + d] = fabsf(a[d] - c[d]);
    }
}

// ---------------------------------------------------------------------------
// Kernel 4: attribute matching (ragged segment softmax + weighted cmp sum).
// ---------------------------------------------------------------------------
__global__ __launch_bounds__(256) void attr_match_kernel(
    const float* __restrict__ Lg, const float* __restrict__ Rg,
    const float* __restrict__ lcmp, const float* __restrict__ rcmp,
    const int* __restrict__ lensL, const int* __restrict__ lensR,
    const float* __restrict__ embL, const float* __restrict__ embR,
    const float* __restrict__ emptyRes,
    float* __restrict__ x)
{
    __shared__ float logits[512];
    __shared__ float red[256];

    const int b    = blockIdx.x;
    const int side = b >> 3;
    const int a    = b & 7;
    const int t    = threadIdx.x;

    const int*   lens = side ? lensR : lensL;
    const float* toks = side ? Rg   : Lg;
    const float* cmp  = side ? rcmp : lcmp;
    const float* femb = (side ? embR : embL) + a * DIM;
    float* outp = x + (side * 8 + a) * DIM;

    int start = 0;
    for (int q = 0; q < a; ++q) start += lens[q];
    const int len = lens[a];

    if (len == 0) {
        for (int d = t; d < DIM; d += 256) outp[d] = emptyRes[d];
        return;
    }

    for (int tok = t; tok < len; tok += 256) {
        const float* tr = toks + (start + tok) * DIM;
        float s = 0.f;
        for (int d = 0; d < DIM; ++d) s = fmaf(tr[d], femb[d], s);
        logits[tok] = s;
    }
    __syncthreads();

    float m = -INFINITY;
    for (int tok = t; tok < len; tok += 256) m = fmaxf(m, logits[tok]);
    red[t] = m; __syncthreads();
    for (int off = 128; off; off >>= 1) {
        if (t < off) red[t] = fmaxf(red[t], red[t + off]);
        __syncthreads();
    }
    m = red[0]; __syncthreads();

    float sum = 0.f;
    for (int tok = t; tok < len; tok += 256) {
        float e = expf(logits[tok] - m);
        logits[tok] = e;
        sum += e;
    }
    red[t] = sum; __syncthreads();
    for (int off = 128; off; off >>= 1) {
        if (t < off) red[t] += red[t + off];
        __syncthreads();
    }
    const float inv = 1.f / red[0];
    __syncthreads();

    for (int d = t; d < DIM; d += 256) {
        float accv = 0.f;
        for (int tok = 0; tok < len; ++tok)
            accv = fmaf(logits[tok] * inv, cmp[(start + tok) * DIM + d], accv);
        outp[d] = accv;
    }
}

// ---------------------------------------------------------------------------
// Kernel 5: entity highway matvec partials (split-K, deterministic).
// ---------------------------------------------------------------------------
__global__ __launch_bounds__(256) void ent_partial_kernel(
    const float* __restrict__ Wn, const float* __restrict__ Wg,
    const float* __restrict__ x, float* __restrict__ partial)
{
    __shared__ float xs[384];
    const int ob   = blockIdx.x;   // 12
    const int slab = blockIdx.y;   // 32
    const int mat  = blockIdx.z;   // 2
    const float* W = mat ? Wg : Wn;
    const int t  = threadIdx.x;
    const int o0 = ob * 1024 + t * 4;
    const int in0 = slab * 384;

    for (int i = t; i < 384; i += 256) xs[i] = x[in0 + i];
    __syncthreads();

    float4 acc = {0.f, 0.f, 0.f, 0.f};
    for (int in = 0; in < 384; ++in) {
        const float  xv = xs[in];
        const float4 w  = *(const float4*)(W + (size_t)(in0 + in) * EDIM + o0);
        acc.x = fmaf(xv, w.x, acc.x);
        acc.y = fmaf(xv, w.y, acc.y);
        acc.z = fmaf(xv, w.z, acc.z);
        acc.w = fmaf(xv, w.w, acc.w);
    }
    *(float4*)(partial + ((size_t)mat * 32 + slab) * EDIM + o0) = acc;
}

// ---------------------------------------------------------------------------
// Kernel 6: reduce the 32 split-K partials.
// ---------------------------------------------------------------------------
__global__ __launch_bounds__(256) void ent_reduce_kernel(
    const float* __restrict__ partial, float* __restrict__ hsum)
{
    const int mat = blockIdx.y;
    const int o   = blockIdx.x * 1024 + threadIdx.x * 4;
    float4 acc = {0.f, 0.f, 0.f, 0.f};
    for (int s = 0; s < 32; ++s) {
        const float4 p = *(const float4*)(partial + ((size_t)mat * 32 + s) * EDIM + o);
        acc.x += p.x; acc.y += p.y; acc.z += p.z; acc.w += p.w;
    }
    *(float4*)(hsum + (size_t)mat * EDIM + o) = acc;
}

// ---------------------------------------------------------------------------
// Kernel 7: entity highway epilogue + final linear + softmax.
// ---------------------------------------------------------------------------
__global__ __launch_bounds__(256) void finalize_kernel(
    const float* __restrict__ hsum, const float* __restrict__ x,
    const float* __restrict__ bn, const float* __restrict__ bg,
    const float* __restrict__ Wl2, const float* __restrict__ bl2,
    float* __restrict__ out)
{
    __shared__ float r0[256], r1[256];
    const int t = threadIdx.x;
    float l0 = 0.f, l1 = 0.f;
    for (int d = t; d < EDIM; d += 256) {
        float h  = fmaxf(hsum[d] + bn[d], 0.f);
        float gv = 1.f / (1.f + expf(-(hsum[EDIM + d] + bg[d])));
        float hw = gv * h + (1.f - gv) * x[d];
        l0 = fmaf(hw, Wl2[d * 2 + 0], l0);
        l1 = fmaf(hw, Wl2[d * 2 + 1], l1);
    }
    r0[t] = l0; r1[t] = l1; __syncthreads();
    for (int off = 128; off; off >>= 1) {
        if (t < off) { r0[t] += r0[t + off]; r1[t] += r1[t + off]; }
        __syncthreads();
    }
    if (t == 0) {
        float a = r0[0] + bl2[0];
        float b = r1[0] + bl2[1];
        float m  = fmaxf(a, b);
        float ea = expf(a - m), eb = expf(b - m);
        float inv = 1.f / (ea + eb);
        out[0] = ea * inv;
        out[1] = eb * inv;
    }
}

// ---------------------------------------------------------------------------
extern "C" void kernel_launch(void* const* d_in, const int* in_sizes, int n_in,
                              void* d_out, int out_size, void* d_ws, size_t ws_size,
                              hipStream_t stream)
{
    const float* Lg     = (const float*)d_in[0];
    const float* Rg     = (const float*)d_in[1];
    const int*   lensL  = (const int*)  d_in[2];
    const int*   lensR  = (const int*)  d_in[3];
    const float* tWn    = (const float*)d_in[4];
    const float* tbn    = (const float*)d_in[5];
    const float* tWg    = (const float*)d_in[6];
    const float* tbg    = (const float*)d_in[7];
    const float* tWl    = (const float*)d_in[8];
    // d_in[9] = lin_tok_b : constant score shift, irrelevant to argmax
    const float* embL   = (const float*)d_in[10];
    const float* embR   = (const float*)d_in[11];
    const float* eWn    = (const float*)d_in[12];
    const float* ebn    = (const float*)d_in[13];
    const float* eWg    = (const float*)d_in[14];
    const float* ebg    = (const float*)d_in[15];
    const float* eWl    = (const float*)d_in[16];
    const float* ebl    = (const float*)d_in[17];
    const float* emptyR = (const float*)d_in[18];
    float* out = (float*)d_out;

    // workspace layout (bytes):
    //   [0, 4718592)        wsplit (4 x 768^2 bf16)   — dead after scores_kernel
    //     aliased later: lcmp [0,1.5M) + rcmp [1.5M,3M) — dead after attr_match
    //     aliased later: ent partial [0, 3M)
    //   [4718592, +1MB)     scores
    //   [5767168, +4KB)     idxL/idxR
    //   [5771264, +48KB)    xcat
    //   [5820416, +96KB)    hsum
    char* ws = (char*)d_ws;
    u16*   wsplit  = (u16*)ws;
    float* scores  = (float*)(ws + 4718592);
    int*   idxL    = (int*)(ws + 5767168);
    int*   idxR    = idxL + 512;
    float* xcat    = (float*)(ws + 5771264);
    float* hsum    = (float*)(ws + 5820416);
    float* lcmp    = (float*)ws;
    float* rcmp    = lcmp + (size_t)LTOK * DIM;
    float* partial = (float*)ws;

    wsplit_kernel<<<dim3(288), 256, 0, stream>>>(tWn, tWg, wsplit);

    scores_kernel<<<dim3(LTOK / 64, RTOK / 4), 256, 0, stream>>>(
        Lg, Rg, wsplit, tbn, tbg, tWl, scores);

    argmax_kernel<<<dim3(LTOK + RTOK), 64, 0, stream>>>(scores, idxL, idxR);

    build_cmp_kernel<<<dim3(LTOK + RTOK), 256, 0, stream>>>(
        Lg, Rg, idxL, idxR, lcmp, rcmp);

    attr_match_kernel<<<dim3(16), 256, 0, stream>>>(
        Lg, Rg, lcmp, rcmp, lensL, lensR, embL, embR, emptyR, xcat);

    ent_partial_kernel<<<dim3(EDIM / 1024, 32, 2), 256, 0, stream>>>(
        eWn, eWg, xcat, partial);

    ent_reduce_kernel<<<dim3(EDIM / 1024, 2), 256, 0, stream>>>(partial, hsum);

    finalize_kernel<<<dim3(1), 256, 0, stream>>>(
        hsum, xcat, ebn, ebg, eWl, ebl, out);
}

// Round 7
// 2123.317 us; speedup vs baseline: 1.2577x; 1.2577x over previous
//
#include <hip/hip_runtime.h>
#include <cmath>

#define NL 8
#define NR 8
#define DIM 768
#define LTOK 512
#define RTOK 512
#define EDIM 12288   // (NL+NR)*DIM
#define KST 32       // K per pipeline stage

typedef unsigned short u16;
typedef __bf16 bf16x8 __attribute__((ext_vector_type(8)));
typedef float  f32x16 __attribute__((ext_vector_type(16)));

#define WARR 589824          // 768*768 elements per split array
// frag-major layout for W (per array): idx(k,d) = ((k>>3)*768 + d)*8 + (k&7)

// RNE split of f32 into bf16 hi + bf16 lo (x ~= hi + lo; residual exact in f32)
__device__ __forceinline__ void splitbf(float c, u16& hi, u16& lo) {
    __bf16 h = (__bf16)c;
    __bf16 l = (__bf16)(c - (float)h);
    hi = __builtin_bit_cast(u16, h);
    lo = __builtin_bit_cast(u16, l);
}

__device__ __forceinline__ void gll16(const void* gsrc, void* lds) {
    __builtin_amdgcn_global_load_lds(
        (const __attribute__((address_space(1))) unsigned int*)gsrc,
        (__attribute__((address_space(3))) unsigned int*)lds, 16, 0, 0);
}

// ---------------------------------------------------------------------------
// Kernel 0: pre-split token-matching weights into bf16 hi/lo, frag-major.
// ---------------------------------------------------------------------------
__global__ __launch_bounds__(256) void wsplit_kernel(
    const float* __restrict__ Wn, const float* __restrict__ Wg, u16* __restrict__ out)
{
    const int gid = blockIdx.x * 256 + threadIdx.x;   // 768 d x 96 kg = 73728
    const int d  = gid % DIM;
    const int kg = gid / DIM;
    u16 hn[8], ln[8], hg[8], lg2[8];
#pragma unroll
    for (int e = 0; e < 8; ++e) {
        splitbf(Wn[(size_t)(kg * 8 + e) * DIM + d], hn[e], ln[e]);
        splitbf(Wg[(size_t)(kg * 8 + e) * DIM + d], hg[e], lg2[e]);
    }
    const size_t fo = ((size_t)kg * DIM + d) * 8;
    *(uint4*)&out[fo]            = *(uint4*)hn;
    *(uint4*)&out[WARR + fo]     = *(uint4*)ln;
    *(uint4*)&out[2 * WARR + fo] = *(uint4*)hg;
    *(uint4*)&out[3 * WARR + fo] = *(uint4*)lg2;
}

// ---------------------------------------------------------------------------
// Kernel 0b: transpose L into Lt[k][i]  (768 x 512) so lT staging is linear.
// ---------------------------------------------------------------------------
__global__ __launch_bounds__(256) void ltrans_kernel(
    const float* __restrict__ Lg, float* __restrict__ Lt)
{
    __shared__ float tile[32][33];
    const int tx  = threadIdx.x & 31;
    const int ty4 = threadIdx.x >> 5;          // 8 groups of 4 rows
    const int k0 = blockIdx.x * 32, i0 = blockIdx.y * 32;
#pragma unroll
    for (int rr = 0; rr < 4; ++rr) {
        int iy = ty4 * 4 + rr;
        tile[iy][tx] = Lg[(size_t)(i0 + iy) * DIM + k0 + tx];
    }
    __syncthreads();
#pragma unroll
    for (int rr = 0; rr < 4; ++rr) {
        int ky = ty4 * 4 + rr;
        Lt[(size_t)(k0 + ky) * LTOK + i0 + tx] = tile[tx][ky];
    }
}

// ---------------------------------------------------------------------------
// Kernel 1: token-matching scores via bf16x3 split MFMA (32x32x16).
// v4: ALL staging via global_load_lds (W triple-buffered 2-ahead, lT from
// pre-transposed Lt double-buffered 1-ahead), counted vmcnt(4) + raw barrier
// so 4 W-loads stay in flight across every barrier. No reg staging -> no
// spill. Math/layouts identical to the absmax-0 round-4/5 kernels.
// ---------------------------------------------------------------------------
__global__ __launch_bounds__(256, 2) void scores_kernel(
    const float* __restrict__ Lg, const float* __restrict__ Rg,
    const float* __restrict__ Lt,
    const u16* __restrict__ wfrag,
    const float* __restrict__ bn, const float* __restrict__ bg,
    const float* __restrict__ Wl,
    float* __restrict__ scores)
{
    __shared__ u16   wLDS[3 * 8192];    // 48 KB: [buf][arr4][kg4][d64][e8]
    __shared__ float lLDS[2 * 2048];    // 16 KB: [buf][k32][i64] (transposed)
    __shared__ float rLDS[4 * 768];     // 12 KB: [j][k] full-K resident

    const int t    = threadIdx.x;
    const int lane = t & 63;
    const int wid  = t >> 6;
    const int l31  = lane & 31;
    const int kh   = lane >> 5;
    const int i0   = blockIdx.x * 64;
    const int j0   = blockIdx.y * 4;
    const int j    = j0 + wid;

    const ptrdiff_t WSTEP = (ptrdiff_t)4 * DIM * 8;          // kgb += 4
    const ptrdiff_t WROLL = (ptrdiff_t)(64 - 92 * DIM) * 8;  // kgb 92->0, dg += 64

    // W sources (per-lane): chunk it*4+wid -> arr=it, kg=wid
    const u16* wp[4];
#pragma unroll
    for (int it = 0; it < 4; ++it)
        wp[it] = wfrag + (size_t)it * WARR + ((size_t)wid * DIM + lane) * 8;

    // lT source (per-lane): unit idx = r*256+t covers k_local=idx>>4, i=(idx&15)*4
    const float* apL = Lt + (size_t)(t >> 4) * LTOK + i0 + (t & 15) * 4;

    // ---- prologue: issue lT(0), W(0), rT, W(1); wait all but W(1) ----
    gll16(apL,        lLDS + wid * 256);
    gll16(apL + 8192, lLDS + 1024 + wid * 256);
#pragma unroll
    for (int it = 0; it < 4; ++it)
        gll16(wp[it], wLDS + (it * 4 + wid) * 512);
#pragma unroll
    for (int r = 0; r < 3; ++r) {
        int idx = r * 256 + t;
        gll16(Rg + (size_t)(j0 + idx / 192) * DIM + (idx % 192) * 4,
              rLDS + r * 1024 + wid * 256);
    }
#pragma unroll
    for (int it = 0; it < 4; ++it)
        gll16(wp[it] + WSTEP, wLDS + 8192 + (it * 4 + wid) * 512);

    // advance to steady-state targets: wp -> stage 2, apL -> stage 1 (k=32)
#pragma unroll
    for (int it = 0; it < 4; ++it) wp[it] += 2 * WSTEP;
    apL += 16384;

    asm volatile("s_waitcnt vmcnt(4)" ::: "memory");
    __builtin_amdgcn_s_barrier();

    float sacc[2][16];
#pragma unroll
    for (int tile = 0; tile < 2; ++tile)
#pragma unroll
        for (int r = 0; r < 16; ++r) sacc[tile][r] = 0.f;

    f32x16 acc[2][2][2];                        // [tile][mat][nd]
#pragma unroll
    for (int tile = 0; tile < 2; ++tile)
#pragma unroll
        for (int mat = 0; mat < 2; ++mat)
#pragma unroll
            for (int nd = 0; nd < 2; ++nd)
#pragma unroll
                for (int r = 0; r < 16; ++r) acc[tile][mat][nd][r] = 0.f;

    int ksC = 0, k0C = 0, dg = 0, lRd = 0;
    const u16* wRd = wLDS;
    u16*       wWr = wLDS + 2 * 8192;
    const u16* const wEndc = wLDS + 3 * 8192;

#pragma unroll 1
    for (int s = 0; s < 288; ++s) {
        // ---- issue next-stage loads (lT first, then W: vmcnt(4) drains lT) ----
        if (s < 287) {
            float* lwb = lLDS + (lRd ^ 1) * 2048 + wid * 256;
            gll16(apL,        lwb);
            gll16(apL + 8192, lwb + 1024);
            apL += (ksC == 22) ? (ptrdiff_t)-376832 : (ptrdiff_t)16384;
        }
        if (s < 286) {
#pragma unroll
            for (int it = 0; it < 4; ++it)
                gll16(wp[it], wWr + (it * 4 + wid) * 512);
            const ptrdiff_t adv = (ksC == 21) ? WROLL : WSTEP;
#pragma unroll
            for (int it = 0; it < 4; ++it) wp[it] += adv;
        }

        // ---- compute current stage ----
        {
            const float* rrow = rLDS + wid * 768 + k0C + kh * 8;
            const float* lb   = lLDS + lRd * 2048 + kh * 512;
#pragma unroll
            for (int kk = 0; kk < 2; ++kk) {
                float rv[8];
#pragma unroll
                for (int e = 0; e < 8; e += 2) {
                    float2 p = *(const float2*)(rrow + kk * 16 + e);
                    rv[e] = p.x; rv[e + 1] = p.y;
                }
                bf16x8 ah[2], al[2];
#pragma unroll
                for (int tile = 0; tile < 2; ++tile) {
                    const float* lp = lb + kk * 1024 + tile * 32 + l31;
#pragma unroll
                    for (int e = 0; e < 8; ++e) {
                        float c = fabsf(lp[e * 64] - rv[e]);
                        __bf16 h = (__bf16)c;
                        ah[tile][e] = h;
                        al[tile][e] = (__bf16)(c - (float)h);
                    }
                }
#pragma unroll
                for (int mat = 0; mat < 2; ++mat)
#pragma unroll
                    for (int nd = 0; nd < 2; ++nd) {
                        const int base = (mat * 2) * 2048 + (kk * 2 + kh) * 512
                                       + (nd * 32 + l31) * 8;
                        bf16x8 whi = *(const bf16x8*)&wRd[base];
                        bf16x8 wlo = *(const bf16x8*)&wRd[base + 2048];
#pragma unroll
                        for (int tile = 0; tile < 2; ++tile) {
                            acc[tile][mat][nd] = __builtin_amdgcn_mfma_f32_32x32x16_bf16(
                                ah[tile], whi, acc[tile][mat][nd], 0, 0, 0);
                            acc[tile][mat][nd] = __builtin_amdgcn_mfma_f32_32x32x16_bf16(
                                al[tile], whi, acc[tile][mat][nd], 0, 0, 0);
                            acc[tile][mat][nd] = __builtin_amdgcn_mfma_f32_32x32x16_bf16(
                                ah[tile], wlo, acc[tile][mat][nd], 0, 0, 0);
                        }
                    }
            }
        }

        if (ksC == 23) {
            // sweep epilogue: nonlinearity + score accum for d in [dg,dg+64)
            // C layout (32x32): col(d) = lane&31, row(i) = (reg&3)+8*(reg>>2)+4*kh
#pragma unroll
            for (int nd = 0; nd < 2; ++nd) {
                const int dd = dg + nd * 32 + l31;
                const float bnv = bn[dd], bgv = bg[dd], wlv = Wl[dd];
                const float rvv = Rg[(size_t)j * DIM + dd];
#pragma unroll
                for (int tile = 0; tile < 2; ++tile)
#pragma unroll
                    for (int r = 0; r < 16; ++r) {
                        const int m = (r & 3) + 8 * (r >> 2) + 4 * kh;
                        const int i = i0 + tile * 32 + m;
                        float h  = fmaxf(acc[tile][0][nd][r] + bnv, 0.f);
                        float g  = 1.f / (1.f + __expf(-(acc[tile][1][nd][r] + bgv)));
                        float cc = fabsf(Lg[(size_t)i * DIM + dd] - rvv);
                        sacc[tile][r] = fmaf(wlv, fmaf(g, h - cc, cc), sacc[tile][r]);
                    }
            }
#pragma unroll
            for (int tile = 0; tile < 2; ++tile)
#pragma unroll
                for (int mat = 0; mat < 2; ++mat)
#pragma unroll
                    for (int nd = 0; nd < 2; ++nd)
#pragma unroll
                        for (int r = 0; r < 16; ++r) acc[tile][mat][nd][r] = 0.f;
        }

        // ---- counted-vmcnt barrier: keep W(s+2) in flight ----
        if (s == 286) { asm volatile("s_waitcnt vmcnt(0)" ::: "memory"); }
        else         { asm volatile("s_waitcnt vmcnt(4)" ::: "memory"); }
        __builtin_amdgcn_s_barrier();

        lRd ^= 1;
        wRd += 8192; if (wRd == wEndc) wRd = wLDS;
        wWr += 8192; if (wWr == (u16*)wEndc) wWr = wLDS;
        ++ksC; k0C += KST;
        if (ksC == 24) { ksC = 0; k0C = 0; dg += 64; }
    }

    // reduce sacc over the 32 lanes of each half (d direction), write scores
#pragma unroll
    for (int tile = 0; tile < 2; ++tile)
#pragma unroll
        for (int r = 0; r < 16; ++r) {
            float v = sacc[tile][r];
            v += __shfl_xor(v, 1);  v += __shfl_xor(v, 2);
            v += __shfl_xor(v, 4);  v += __shfl_xor(v, 8);
            v += __shfl_xor(v, 16);
            if (l31 == 0) {
                const int m = (r & 3) + 8 * (r >> 2) + 4 * kh;
                scores[(size_t)(i0 + tile * 32 + m) * RTOK + j] = v;
            }
        }
}

// ---------------------------------------------------------------------------
// Kernel 2: argmax per row (left) and per column (right); first-occurrence ties.
// ---------------------------------------------------------------------------
__global__ __launch_bounds__(64) void argmax_kernel(
    const float* __restrict__ scores, int* __restrict__ idxL, int* __restrict__ idxR)
{
    const int b = blockIdx.x;          // 0..511 rows, 512..1023 cols
    const int t = threadIdx.x;
    const bool isRow = (b < LTOK);
    const int  n = b & (LTOK - 1);

    float best = -INFINITY;
    int   bidx = 0x7fffffff;
    for (int s = t; s < 512; s += 64) {
        float v = isRow ? scores[n * RTOK + s] : scores[s * RTOK + n];
        if (v > best) { best = v; bidx = s; }
    }
#pragma unroll
    for (int off = 32; off; off >>= 1) {
        float ob = __shfl_down(best, off);
        int   oi = __shfl_down(bidx, off);
        if (ob > best || (ob == best && oi < bidx)) { best = ob; bidx = oi; }
    }
    if (t == 0) (isRow ? idxL : idxR)[n] = bidx;
}

// ---------------------------------------------------------------------------
// Kernel 3: gather chosen cmp rows.
// ---------------------------------------------------------------------------
__global__ __launch_bounds__(256) void build_cmp_kernel(
    const float* __restrict__ Lg, const float* __restrict__ Rg,
    const int* __restrict__ idxL, const int* __restrict__ idxR,
    float* __restrict__ lcmp, float* __restrict__ rcmp)
{
    const int b = blockIdx.x;
    const int t = threadIdx.x;
    if (b < LTOK) {
        const float* a = Lg + b * DIM;
        const float* c = Rg + idxL[b] * DIM;
        for (int d = t; d < DIM; d += 256) lcmp[b * DIM + d] = fabsf(a[d] - c[d]);
    } else {
        const int jj = b - LTOK;
        const float* a = Rg + jj * DIM;
        const float* c = Lg + idxR[jj] * DIM;
        for (int d = t; d < DIM; d += 256) rcmp[jj * DIM + d] = fabsf(a[d] - c[d]);
    }
}

// ---------------------------------------------------------------------------
// Kernel 4: attribute matching (ragged segment softmax + weighted cmp sum).
// ---------------------------------------------------------------------------
__global__ __launch_bounds__(256) void attr_match_kernel(
    const float* __restrict__ Lg, const float* __restrict__ Rg,
    const float* __restrict__ lcmp, const float* __restrict__ rcmp,
    const int* __restrict__ lensL, const int* __restrict__ lensR,
    const float* __restrict__ embL, const float* __restrict__ embR,
    const float* __restrict__ emptyRes,
    float* __restrict__ x)
{
    __shared__ float logits[512];
    __shared__ float red[256];

    const int b    = blockIdx.x;
    const int side = b >> 3;
    const int a    = b & 7;
    const int t    = threadIdx.x;

    const int*   lens = side ? lensR : lensL;
    const float* toks = side ? Rg   : Lg;
    const float* cmp  = side ? rcmp : lcmp;
    const float* femb = (side ? embR : embL) + a * DIM;
    float* outp = x + (side * 8 + a) * DIM;

    int start = 0;
    for (int q = 0; q < a; ++q) start += lens[q];
    const int len = lens[a];

    if (len == 0) {
        for (int d = t; d < DIM; d += 256) outp[d] = emptyRes[d];
        return;
    }

    for (int tok = t; tok < len; tok += 256) {
        const float* tr = toks + (start + tok) * DIM;
        float s = 0.f;
        for (int d = 0; d < DIM; ++d) s = fmaf(tr[d], femb[d], s);
        logits[tok] = s;
    }
    __syncthreads();

    float m = -INFINITY;
    for (int tok = t; tok < len; tok += 256) m = fmaxf(m, logits[tok]);
    red[t] = m; __syncthreads();
    for (int off = 128; off; off >>= 1) {
        if (t < off) red[t] = fmaxf(red[t], red[t + off]);
        __syncthreads();
    }
    m = red[0]; __syncthreads();

    float sum = 0.f;
    for (int tok = t; tok < len; tok += 256) {
        float e = expf(logits[tok] - m);
        logits[tok] = e;
        sum += e;
    }
    red[t] = sum; __syncthreads();
    for (int off = 128; off; off >>= 1) {
        if (t < off) red[t] += red[t + off];
        __syncthreads();
    }
    const float inv = 1.f / red[0];
    __syncthreads();

    for (int d = t; d < DIM; d += 256) {
        float accv = 0.f;
        for (int tok = 0; tok < len; ++tok)
            accv = fmaf(logits[tok] * inv, cmp[(start + tok) * DIM + d], accv);
        outp[d] = accv;
    }
}

// ---------------------------------------------------------------------------
// Kernel 5: entity highway matvec partials (split-K, deterministic).
// ---------------------------------------------------------------------------
__global__ __launch_bounds__(256) void ent_partial_kernel(
    const float* __restrict__ Wn, const float* __restrict__ Wg,
    const float* __restrict__ x, float* __restrict__ partial)
{
    __shared__ float xs[384];
    const int ob   = blockIdx.x;   // 12
    const int slab = blockIdx.y;   // 32
    const int mat  = blockIdx.z;   // 2
    const float* W = mat ? Wg : Wn;
    const int t  = threadIdx.x;
    const int o0 = ob * 1024 + t * 4;
    const int in0 = slab * 384;

    for (int i = t; i < 384; i += 256) xs[i] = x[in0 + i];
    __syncthreads();

    float4 acc = {0.f, 0.f, 0.f, 0.f};
    for (int in = 0; in < 384; ++in) {
        const float  xv = xs[in];
        const float4 w  = *(const float4*)(W + (size_t)(in0 + in) * EDIM + o0);
        acc.x = fmaf(xv, w.x, acc.x);
        acc.y = fmaf(xv, w.y, acc.y);
        acc.z = fmaf(xv, w.z, acc.z);
        acc.w = fmaf(xv, w.w, acc.w);
    }
    *(float4*)(partial + ((size_t)mat * 32 + slab) * EDIM + o0) = acc;
}

// ---------------------------------------------------------------------------
// Kernel 6: reduce the 32 split-K partials.
// ---------------------------------------------------------------------------
__global__ __launch_bounds__(256) void ent_reduce_kernel(
    const float* __restrict__ partial, float* __restrict__ hsum)
{
    const int mat = blockIdx.y;
    const int o   = blockIdx.x * 1024 + threadIdx.x * 4;
    float4 acc = {0.f, 0.f, 0.f, 0.f};
    for (int s = 0; s < 32; ++s) {
        const float4 p = *(const float4*)(partial + ((size_t)mat * 32 + s) * EDIM + o);
        acc.x += p.x; acc.y += p.y; acc.z += p.z; acc.w += p.w;
    }
    *(float4*)(hsum + (size_t)mat * EDIM + o) = acc;
}

// ---------------------------------------------------------------------------
// Kernel 7: entity highway epilogue + final linear + softmax.
// ---------------------------------------------------------------------------
__global__ __launch_bounds__(256) void finalize_kernel(
    const float* __restrict__ hsum, const float* __restrict__ x,
    const float* __restrict__ bn, const float* __restrict__ bg,
    const float* __restrict__ Wl2, const float* __restrict__ bl2,
    float* __restrict__ out)
{
    __shared__ float r0[256], r1[256];
    const int t = threadIdx.x;
    float l0 = 0.f, l1 = 0.f;
    for (int d = t; d < EDIM; d += 256) {
        float h  = fmaxf(hsum[d] + bn[d], 0.f);
        float gv = 1.f / (1.f + expf(-(hsum[EDIM + d] + bg[d])));
        float hw = gv * h + (1.f - gv) * x[d];
        l0 = fmaf(hw, Wl2[d * 2 + 0], l0);
        l1 = fmaf(hw, Wl2[d * 2 + 1], l1);
    }
    r0[t] = l0; r1[t] = l1; __syncthreads();
    for (int off = 128; off; off >>= 1) {
        if (t < off) { r0[t] += r0[t + off]; r1[t] += r1[t + off]; }
        __syncthreads();
    }
    if (t == 0) {
        float a = r0[0] + bl2[0];
        float b = r1[0] + bl2[1];
        float m  = fmaxf(a, b);
        float ea = expf(a - m), eb = expf(b - m);
        float inv = 1.f / (ea + eb);
        out[0] = ea * inv;
        out[1] = eb * inv;
    }
}

// ---------------------------------------------------------------------------
extern "C" void kernel_launch(void* const* d_in, const int* in_sizes, int n_in,
                              void* d_out, int out_size, void* d_ws, size_t ws_size,
                              hipStream_t stream)
{
    const float* Lg     = (const float*)d_in[0];
    const float* Rg     = (const float*)d_in[1];
    const int*   lensL  = (const int*)  d_in[2];
    const int*   lensR  = (const int*)  d_in[3];
    const float* tWn    = (const float*)d_in[4];
    const float* tbn    = (const float*)d_in[5];
    const float* tWg    = (const float*)d_in[6];
    const float* tbg    = (const float*)d_in[7];
    const float* tWl    = (const float*)d_in[8];
    // d_in[9] = lin_tok_b : constant score shift, irrelevant to argmax
    const float* embL   = (const float*)d_in[10];
    const float* embR   = (const float*)d_in[11];
    const float* eWn    = (const float*)d_in[12];
    const float* ebn    = (const float*)d_in[13];
    const float* eWg    = (const float*)d_in[14];
    const float* ebg    = (const float*)d_in[15];
    const float* eWl    = (const float*)d_in[16];
    const float* ebl    = (const float*)d_in[17];
    const float* emptyR = (const float*)d_in[18];
    float* out = (float*)d_out;

    // workspace layout (bytes):
    //   [0, 4718592)        wsplit (4 x 768^2 bf16)   — dead after scores_kernel
    //     aliased later: lcmp [0,1.5M) + rcmp [1.5M,3M) — dead after attr_match
    //     aliased later: ent partial [0, 3M)
    //   [4718592, +1MB)     scores
    //   [5767168, +4KB)     idxL/idxR
    //   [5771264, +48KB)    xcat
    //   [5820416, +96KB)    hsum
    //   [5918720, +1.5MB)   Lt (transposed L)         — dead after scores_kernel
    char* ws = (char*)d_ws;
    u16*   wsplit  = (u16*)ws;
    float* scores  = (float*)(ws + 4718592);
    int*   idxL    = (int*)(ws + 5767168);
    int*   idxR    = idxL + 512;
    float* xcat    = (float*)(ws + 5771264);
    float* hsum    = (float*)(ws + 5820416);
    float* Lt      = (float*)(ws + 5918720);
    float* lcmp    = (float*)ws;
    float* rcmp    = lcmp + (size_t)LTOK * DIM;
    float* partial = (float*)ws;

    wsplit_kernel<<<dim3(288), 256, 0, stream>>>(tWn, tWg, wsplit);

    ltrans_kernel<<<dim3(DIM / 32, LTOK / 32), 256, 0, stream>>>(Lg, Lt);

    scores_kernel<<<dim3(LTOK / 64, RTOK / 4), 256, 0, stream>>>(
        Lg, Rg, Lt, wsplit, tbn, tbg, tWl, scores);

    argmax_kernel<<<dim3(LTOK + RTOK), 64, 0, stream>>>(scores, idxL, idxR);

    build_cmp_kernel<<<dim3(LTOK + RTOK), 256, 0, stream>>>(
        Lg, Rg, idxL, idxR, lcmp, rcmp);

    attr_match_kernel<<<dim3(16), 256, 0, stream>>>(
        Lg, Rg, lcmp, rcmp, lensL, lensR, embL, embR, emptyR, xcat);

    ent_partial_kernel<<<dim3(EDIM / 1024, 32, 2), 256, 0, stream>>>(
        eWn, eWg, xcat, partial);

    ent_reduce_kernel<<<dim3(EDIM / 1024, 2), 256, 0, stream>>>(partial, hsum);

    finalize_kernel<<<dim3(1), 256, 0, stream>>>(
        hsum, xcat, ebn, ebg, eWl, ebl, out);
}

// Round 8
// 2099.470 us; speedup vs baseline: 1.2720x; 1.0114x over previous
//
#include <hip/hip_runtime.h>
#include <cmath>

#define NL 8
#define NR 8
#define DIM 768
#define LTOK 512
#define RTOK 512
#define EDIM 12288   // (NL+NR)*DIM
#define KST 32       // K per pipeline stage

typedef unsigned short u16;
typedef __bf16 bf16x8 __attribute__((ext_vector_type(8)));
typedef float  f32x16 __attribute__((ext_vector_type(16)));

#define WARR 589824          // 768*768 elements per split array
// frag-major layout for W (per array): idx(k,d) = ((k>>3)*768 + d)*8 + (k&7)

// RNE split of f32 into bf16 hi + bf16 lo (x ~= hi + lo; residual exact in f32)
__device__ __forceinline__ void splitbf(float c, u16& hi, u16& lo) {
    __bf16 h = (__bf16)c;
    __bf16 l = (__bf16)(c - (float)h);
    hi = __builtin_bit_cast(u16, h);
    lo = __builtin_bit_cast(u16, l);
}

__device__ __forceinline__ void gll16(const void* gsrc, void* lds) {
    __builtin_amdgcn_global_load_lds(
        (const __attribute__((address_space(1))) unsigned int*)gsrc,
        (__attribute__((address_space(3))) unsigned int*)lds, 16, 0, 0);
}

// ---------------------------------------------------------------------------
// Kernel 0: pre-split token-matching weights into bf16 hi/lo, frag-major.
// ---------------------------------------------------------------------------
__global__ __launch_bounds__(256) void wsplit_kernel(
    const float* __restrict__ Wn, const float* __restrict__ Wg, u16* __restrict__ out)
{
    const int gid = blockIdx.x * 256 + threadIdx.x;   // 768 d x 96 kg = 73728
    const int d  = gid % DIM;
    const int kg = gid / DIM;
    u16 hn[8], ln[8], hg[8], lg2[8];
#pragma unroll
    for (int e = 0; e < 8; ++e) {
        splitbf(Wn[(size_t)(kg * 8 + e) * DIM + d], hn[e], ln[e]);
        splitbf(Wg[(size_t)(kg * 8 + e) * DIM + d], hg[e], lg2[e]);
    }
    const size_t fo = ((size_t)kg * DIM + d) * 8;
    *(uint4*)&out[fo]            = *(uint4*)hn;
    *(uint4*)&out[WARR + fo]     = *(uint4*)ln;
    *(uint4*)&out[2 * WARR + fo] = *(uint4*)hg;
    *(uint4*)&out[3 * WARR + fo] = *(uint4*)lg2;
}

// ---------------------------------------------------------------------------
// Kernel 0b: transpose L into Lt[k][i]  (768 x 512) so lT staging is linear.
// ---------------------------------------------------------------------------
__global__ __launch_bounds__(256) void ltrans_kernel(
    const float* __restrict__ Lg, float* __restrict__ Lt)
{
    __shared__ float tile[32][33];
    const int tx  = threadIdx.x & 31;
    const int ty4 = threadIdx.x >> 5;          // 8 groups of 4 rows
    const int k0 = blockIdx.x * 32, i0 = blockIdx.y * 32;
#pragma unroll
    for (int rr = 0; rr < 4; ++rr) {
        int iy = ty4 * 4 + rr;
        tile[iy][tx] = Lg[(size_t)(i0 + iy) * DIM + k0 + tx];
    }
    __syncthreads();
#pragma unroll
    for (int rr = 0; rr < 4; ++rr) {
        int ky = ty4 * 4 + rr;
        Lt[(size_t)(k0 + ky) * LTOK + i0 + tx] = tile[tx][ky];
    }
}

// ---------------------------------------------------------------------------
// Kernel 1: token-matching scores via bf16x3 split MFMA (32x32x16).
// v5 = v4 (counted vmcnt(4) + triple-buffered W + double-buffered lT, all
// staging via global_load_lds) plus:
//   - s_setprio(1) around each MFMA cluster (2 independent blocks/CU ->
//     scheduler can favor the MFMA-entering block)
//   - VMEM issue split across the two kk sub-phases (lT before kk0,
//     W between kk0 and kk1) instead of one burst at stage top.
// Queue order (lT before W within a stage) unchanged -> vmcnt(4) still
// leaves exactly W(s+2) in flight. Math identical to the absmax-0 kernels.
// ---------------------------------------------------------------------------
__global__ __launch_bounds__(256, 2) void scores_kernel(
    const float* __restrict__ Lg, const float* __restrict__ Rg,
    const float* __restrict__ Lt,
    const u16* __restrict__ wfrag,
    const float* __restrict__ bn, const float* __restrict__ bg,
    const float* __restrict__ Wl,
    float* __restrict__ scores)
{
    __shared__ u16   wLDS[3 * 8192];    // 48 KB: [buf][arr4][kg4][d64][e8]
    __shared__ float lLDS[2 * 2048];    // 16 KB: [buf][k32][i64] (transposed)
    __shared__ float rLDS[4 * 768];     // 12 KB: [j][k] full-K resident

    const int t    = threadIdx.x;
    const int lane = t & 63;
    const int wid  = t >> 6;
    const int l31  = lane & 31;
    const int kh   = lane >> 5;
    const int i0   = blockIdx.x * 64;
    const int j0   = blockIdx.y * 4;
    const int j    = j0 + wid;

    const ptrdiff_t WSTEP = (ptrdiff_t)4 * DIM * 8;          // kgb += 4
    const ptrdiff_t WROLL = (ptrdiff_t)(64 - 92 * DIM) * 8;  // kgb 92->0, dg += 64

    // W sources (per-lane): chunk it*4+wid -> arr=it, kg=wid
    const u16* wp[4];
#pragma unroll
    for (int it = 0; it < 4; ++it)
        wp[it] = wfrag + (size_t)it * WARR + ((size_t)wid * DIM + lane) * 8;

    // lT source (per-lane): unit idx = r*256+t covers k_local=idx>>4, i=(idx&15)*4
    const float* apL = Lt + (size_t)(t >> 4) * LTOK + i0 + (t & 15) * 4;

    // ---- prologue: issue lT(0), W(0), rT, W(1); wait all but W(1) ----
    gll16(apL,        lLDS + wid * 256);
    gll16(apL + 8192, lLDS + 1024 + wid * 256);
#pragma unroll
    for (int it = 0; it < 4; ++it)
        gll16(wp[it], wLDS + (it * 4 + wid) * 512);
#pragma unroll
    for (int r = 0; r < 3; ++r) {
        int idx = r * 256 + t;
        gll16(Rg + (size_t)(j0 + idx / 192) * DIM + (idx % 192) * 4,
              rLDS + r * 1024 + wid * 256);
    }
#pragma unroll
    for (int it = 0; it < 4; ++it)
        gll16(wp[it] + WSTEP, wLDS + 8192 + (it * 4 + wid) * 512);

    // advance to steady-state targets: wp -> stage 2, apL -> stage 1 (k=32)
#pragma unroll
    for (int it = 0; it < 4; ++it) wp[it] += 2 * WSTEP;
    apL += 16384;

    asm volatile("s_waitcnt vmcnt(4)" ::: "memory");
    __builtin_amdgcn_s_barrier();

    float sacc[2][16];
#pragma unroll
    for (int tile = 0; tile < 2; ++tile)
#pragma unroll
        for (int r = 0; r < 16; ++r) sacc[tile][r] = 0.f;

    f32x16 acc[2][2][2];                        // [tile][mat][nd]
#pragma unroll
    for (int tile = 0; tile < 2; ++tile)
#pragma unroll
        for (int mat = 0; mat < 2; ++mat)
#pragma unroll
            for (int nd = 0; nd < 2; ++nd)
#pragma unroll
                for (int r = 0; r < 16; ++r) acc[tile][mat][nd][r] = 0.f;

    int ksC = 0, k0C = 0, dg = 0, lRd = 0;
    const u16* wRd = wLDS;
    u16*       wWr = wLDS + 2 * 8192;
    const u16* const wEndc = wLDS + 3 * 8192;

#pragma unroll 1
    for (int s = 0; s < 288; ++s) {
        // one kk sub-phase: A-gen + 24 MFMAs (setprio-wrapped)
        auto phase = [&](int kk) {
            const float* rrow = rLDS + wid * 768 + k0C + kh * 8;
            float rv[8];
#pragma unroll
            for (int e = 0; e < 8; e += 2) {
                float2 p = *(const float2*)(rrow + kk * 16 + e);
                rv[e] = p.x; rv[e + 1] = p.y;
            }
            bf16x8 ah[2], al[2];
            const float* lb = lLDS + lRd * 2048 + kh * 512;
#pragma unroll
            for (int tile = 0; tile < 2; ++tile) {
                const float* lp = lb + kk * 1024 + tile * 32 + l31;
#pragma unroll
                for (int e = 0; e < 8; ++e) {
                    float c = fabsf(lp[e * 64] - rv[e]);
                    __bf16 h = (__bf16)c;
                    ah[tile][e] = h;
                    al[tile][e] = (__bf16)(c - (float)h);
                }
            }
            __builtin_amdgcn_s_setprio(1);
#pragma unroll
            for (int mat = 0; mat < 2; ++mat)
#pragma unroll
                for (int nd = 0; nd < 2; ++nd) {
                    const int base = (mat * 2) * 2048 + (kk * 2 + kh) * 512
                                   + (nd * 32 + l31) * 8;
                    bf16x8 whi = *(const bf16x8*)&wRd[base];
                    bf16x8 wlo = *(const bf16x8*)&wRd[base + 2048];
#pragma unroll
                    for (int tile = 0; tile < 2; ++tile) {
                        acc[tile][mat][nd] = __builtin_amdgcn_mfma_f32_32x32x16_bf16(
                            ah[tile], whi, acc[tile][mat][nd], 0, 0, 0);
                        acc[tile][mat][nd] = __builtin_amdgcn_mfma_f32_32x32x16_bf16(
                            al[tile], whi, acc[tile][mat][nd], 0, 0, 0);
                        acc[tile][mat][nd] = __builtin_amdgcn_mfma_f32_32x32x16_bf16(
                            ah[tile], wlo, acc[tile][mat][nd], 0, 0, 0);
                    }
                }
            __builtin_amdgcn_s_setprio(0);
        };

        // ---- issue lT(s+1), then compute kk=0 ----
        if (s < 287) {
            float* lwb = lLDS + (lRd ^ 1) * 2048 + wid * 256;
            gll16(apL,        lwb);
            gll16(apL + 8192, lwb + 1024);
            apL += (ksC == 22) ? (ptrdiff_t)-376832 : (ptrdiff_t)16384;
        }
        phase(0);

        // ---- issue W(s+2) under kk=0's MFMA shadow, then compute kk=1 ----
        if (s < 286) {
#pragma unroll
            for (int it = 0; it < 4; ++it)
                gll16(wp[it], wWr + (it * 4 + wid) * 512);
            const ptrdiff_t adv = (ksC == 21) ? WROLL : WSTEP;
#pragma unroll
            for (int it = 0; it < 4; ++it) wp[it] += adv;
        }
        phase(1);

        if (ksC == 23) {
            // sweep epilogue: nonlinearity + score accum for d in [dg,dg+64)
            // C layout (32x32): col(d) = lane&31, row(i) = (reg&3)+8*(reg>>2)+4*kh
#pragma unroll
            for (int nd = 0; nd < 2; ++nd) {
                const int dd = dg + nd * 32 + l31;
                const float bnv = bn[dd], bgv = bg[dd], wlv = Wl[dd];
                const float rvv = Rg[(size_t)j * DIM + dd];
#pragma unroll
                for (int tile = 0; tile < 2; ++tile)
#pragma unroll
                    for (int r = 0; r < 16; ++r) {
                        const int m = (r & 3) + 8 * (r >> 2) + 4 * kh;
                        const int i = i0 + tile * 32 + m;
                        float h  = fmaxf(acc[tile][0][nd][r] + bnv, 0.f);
                        float g  = 1.f / (1.f + __expf(-(acc[tile][1][nd][r] + bgv)));
                        float cc = fabsf(Lg[(size_t)i * DIM + dd] - rvv);
                        sacc[tile][r] = fmaf(wlv, fmaf(g, h - cc, cc), sacc[tile][r]);
                    }
            }
#pragma unroll
            for (int tile = 0; tile < 2; ++tile)
#pragma unroll
                for (int mat = 0; mat < 2; ++mat)
#pragma unroll
                    for (int nd = 0; nd < 2; ++nd)
#pragma unroll
                        for (int r = 0; r < 16; ++r) acc[tile][mat][nd][r] = 0.f;
        }

        // ---- counted-vmcnt barrier: keep W(s+2) in flight ----
        if (s == 286) { asm volatile("s_waitcnt vmcnt(0)" ::: "memory"); }
        else         { asm volatile("s_waitcnt vmcnt(4)" ::: "memory"); }
        __builtin_amdgcn_s_barrier();

        lRd ^= 1;
        wRd += 8192; if (wRd == wEndc) wRd = wLDS;
        wWr += 8192; if (wWr == (u16*)wEndc) wWr = wLDS;
        ++ksC; k0C += KST;
        if (ksC == 24) { ksC = 0; k0C = 0; dg += 64; }
    }

    // reduce sacc over the 32 lanes of each half (d direction), write scores
#pragma unroll
    for (int tile = 0; tile < 2; ++tile)
#pragma unroll
        for (int r = 0; r < 16; ++r) {
            float v = sacc[tile][r];
            v += __shfl_xor(v, 1);  v += __shfl_xor(v, 2);
            v += __shfl_xor(v, 4);  v += __shfl_xor(v, 8);
            v += __shfl_xor(v, 16);
            if (l31 == 0) {
                const int m = (r & 3) + 8 * (r >> 2) + 4 * kh;
                scores[(size_t)(i0 + tile * 32 + m) * RTOK + j] = v;
            }
        }
}

// ---------------------------------------------------------------------------
// Kernel 2: argmax per row (left) and per column (right); first-occurrence ties.
// ---------------------------------------------------------------------------
__global__ __launch_bounds__(64) void argmax_kernel(
    const float* __restrict__ scores, int* __restrict__ idxL, int* __restrict__ idxR)
{
    const int b = blockIdx.x;          // 0..511 rows, 512..1023 cols
    const int t = threadIdx.x;
    const bool isRow = (b < LTOK);
    const int  n = b & (LTOK - 1);

    float best = -INFINITY;
    int   bidx = 0x7fffffff;
    for (int s = t; s < 512; s += 64) {
        float v = isRow ? scores[n * RTOK + s] : scores[s * RTOK + n];
        if (v > best) { best = v; bidx = s; }
    }
#pragma unroll
    for (int off = 32; off; off >>= 1) {
        float ob = __shfl_down(best, off);
        int   oi = __shfl_down(bidx, off);
        if (ob > best || (ob == best && oi < bidx)) { best = ob; bidx = oi; }
    }
    if (t == 0) (isRow ? idxL : idxR)[n] = bidx;
}

// ---------------------------------------------------------------------------
// Kernel 3: gather chosen cmp rows.
// ---------------------------------------------------------------------------
__global__ __launch_bounds__(256) void build_cmp_kernel(
    const float* __restrict__ Lg, const float* __restrict__ Rg,
    const int* __restrict__ idxL, const int* __restrict__ idxR,
    float* __restrict__ lcmp, float* __restrict__ rcmp)
{
    const int b = blockIdx.x;
    const int t = threadIdx.x;
    if (b < LTOK) {
        const float* a = Lg + b * DIM;
        const float* c = Rg + idxL[b] * DIM;
        for (int d = t; d < DIM; d += 256) lcmp[b * DIM + d] = fabsf(a[d] - c[d]);
    } else {
        const int jj = b - LTOK;
        const float* a = Rg + jj * DIM;
        const float* c = Lg + idxR[jj] * DIM;
        for (int d = t; d < DIM; d += 256) rcmp[jj * DIM + d] = fabsf(a[d] - c[d]);
    }
}

// ---------------------------------------------------------------------------
// Kernel 4: attribute matching (ragged segment softmax + weighted cmp sum).
// ---------------------------------------------------------------------------
__global__ __launch_bounds__(256) void attr_match_kernel(
    const float* __restrict__ Lg, const float* __restrict__ Rg,
    const float* __restrict__ lcmp, const float* __restrict__ rcmp,
    const int* __restrict__ lensL, const int* __restrict__ lensR,
    const float* __restrict__ embL, const float* __restrict__ embR,
    const float* __restrict__ emptyRes,
    float* __restrict__ x)
{
    __shared__ float logits[512];
    __shared__ float red[256];

    const int b    = blockIdx.x;
    const int side = b >> 3;
    const int a    = b & 7;
    const int t    = threadIdx.x;

    const int*   lens = side ? lensR : lensL;
    const float* toks = side ? Rg   : Lg;
    const float* cmp  = side ? rcmp : lcmp;
    const float* femb = (side ? embR : embL) + a * DIM;
    float* outp = x + (side * 8 + a) * DIM;

    int start = 0;
    for (int q = 0; q < a; ++q) start += lens[q];
    const int len = lens[a];

    if (len == 0) {
        for (int d = t; d < DIM; d += 256) outp[d] = emptyRes[d];
        return;
    }

    for (int tok = t; tok < len; tok += 256) {
        const float* tr = toks + (start + tok) * DIM;
        float s = 0.f;
        for (int d = 0; d < DIM; ++d) s = fmaf(tr[d], femb[d], s);
        logits[tok] = s;
    }
    __syncthreads();

    float m = -INFINITY;
    for (int tok = t; tok < len; tok += 256) m = fmaxf(m, logits[tok]);
    red[t] = m; __syncthreads();
    for (int off = 128; off; off >>= 1) {
        if (t < off) red[t] = fmaxf(red[t], red[t + off]);
        __syncthreads();
    }
    m = red[0]; __syncthreads();

    float sum = 0.f;
    for (int tok = t; tok < len; tok += 256) {
        float e = expf(logits[tok] - m);
        logits[tok] = e;
        sum += e;
    }
    red[t] = sum; __syncthreads();
    for (int off = 128; off; off >>= 1) {
        if (t < off) red[t] += red[t + off];
        __syncthreads();
    }
    const float inv = 1.f / red[0];
    __syncthreads();

    for (int d = t; d < DIM; d += 256) {
        float accv = 0.f;
        for (int tok = 0; tok < len; ++tok)
            accv = fmaf(logits[tok] * inv, cmp[(start + tok) * DIM + d], accv);
        outp[d] = accv;
    }
}

// ---------------------------------------------------------------------------
// Kernel 5: entity highway matvec partials (split-K, deterministic).
// ---------------------------------------------------------------------------
__global__ __launch_bounds__(256) void ent_partial_kernel(
    const float* __restrict__ Wn, const float* __restrict__ Wg,
    const float* __restrict__ x, float* __restrict__ partial)
{
    __shared__ float xs[384];
    const int ob   = blockIdx.x;   // 12
    const int slab = blockIdx.y;   // 32
    const int mat  = blockIdx.z;   // 2
    const float* W = mat ? Wg : Wn;
    const int t  = threadIdx.x;
    const int o0 = ob * 1024 + t * 4;
    const int in0 = slab * 384;

    for (int i = t; i < 384; i += 256) xs[i] = x[in0 + i];
    __syncthreads();

    float4 acc = {0.f, 0.f, 0.f, 0.f};
    for (int in = 0; in < 384; ++in) {
        const float  xv = xs[in];
        const float4 w  = *(const float4*)(W + (size_t)(in0 + in) * EDIM + o0);
        acc.x = fmaf(xv, w.x, acc.x);
        acc.y = fmaf(xv, w.y, acc.y);
        acc.z = fmaf(xv, w.z, acc.z);
        acc.w = fmaf(xv, w.w, acc.w);
    }
    *(float4*)(partial + ((size_t)mat * 32 + slab) * EDIM + o0) = acc;
}

// ---------------------------------------------------------------------------
// Kernel 6: reduce the 32 split-K partials.
// ---------------------------------------------------------------------------
__global__ __launch_bounds__(256) void ent_reduce_kernel(
    const float* __restrict__ partial, float* __restrict__ hsum)
{
    const int mat = blockIdx.y;
    const int o   = blockIdx.x * 1024 + threadIdx.x * 4;
    float4 acc = {0.f, 0.f, 0.f, 0.f};
    for (int s = 0; s < 32; ++s) {
        const float4 p = *(const float4*)(partial + ((size_t)mat * 32 + s) * EDIM + o);
        acc.x += p.x; acc.y += p.y; acc.z += p.z; acc.w += p.w;
    }
    *(float4*)(hsum + (size_t)mat * EDIM + o) = acc;
}

// ---------------------------------------------------------------------------
// Kernel 7: entity highway epilogue + final linear + softmax.
// ---------------------------------------------------------------------------
__global__ __launch_bounds__(256) void finalize_kernel(
    const float* __restrict__ hsum, const float* __restrict__ x,
    const float* __restrict__ bn, const float* __restrict__ bg,
    const float* __restrict__ Wl2, const float* __restrict__ bl2,
    float* __restrict__ out)
{
    __shared__ float r0[256], r1[256];
    const int t = threadIdx.x;
    float l0 = 0.f, l1 = 0.f;
    for (int d = t; d < EDIM; d += 256) {
        float h  = fmaxf(hsum[d] + bn[d], 0.f);
        float gv = 1.f / (1.f + expf(-(hsum[EDIM + d] + bg[d])));
        float hw = gv * h + (1.f - gv) * x[d];
        l0 = fmaf(hw, Wl2[d * 2 + 0], l0);
        l1 = fmaf(hw, Wl2[d * 2 + 1], l1);
    }
    r0[t] = l0; r1[t] = l1; __syncthreads();
    for (int off = 128; off; off >>= 1) {
        if (t < off) { r0[t] += r0[t + off]; r1[t] += r1[t + off]; }
        __syncthreads();
    }
    if (t == 0) {
        float a = r0[0] + bl2[0];
        float b = r1[0] + bl2[1];
        float m  = fmaxf(a, b);
        float ea = expf(a - m), eb = expf(b - m);
        float inv = 1.f / (ea + eb);
        out[0] = ea * inv;
        out[1] = eb * inv;
    }
}

// ---------------------------------------------------------------------------
extern "C" void kernel_launch(void* const* d_in, const int* in_sizes, int n_in,
                              void* d_out, int out_size, void* d_ws, size_t ws_size,
                              hipStream_t stream)
{
    const float* Lg     = (const float*)d_in[0];
    const float* Rg     = (const float*)d_in[1];
    const int*   lensL  = (const int*)  d_in[2];
    const int*   lensR  = (const int*)  d_in[3];
    const float* tWn    = (const float*)d_in[4];
    const float* tbn    = (const float*)d_in[5];
    const float* tWg    = (const float*)d_in[6];
    const float* tbg    = (const float*)d_in[7];
    const float* tWl    = (const float*)d_in[8];
    // d_in[9] = lin_tok_b : constant score shift, irrelevant to argmax
    const float* embL   = (const float*)d_in[10];
    const float* embR   = (const float*)d_in[11];
    const float* eWn    = (const float*)d_in[12];
    const float* ebn    = (const float*)d_in[13];
    const float* eWg    = (const float*)d_in[14];
    const float* ebg    = (const float*)d_in[15];
    const float* eWl    = (const float*)d_in[16];
    const float* ebl    = (const float*)d_in[17];
    const float* emptyR = (const float*)d_in[18];
    float* out = (float*)d_out;

    // workspace layout (bytes):
    //   [0, 4718592)        wsplit (4 x 768^2 bf16)   — dead after scores_kernel
    //     aliased later: lcmp [0,1.5M) + rcmp [1.5M,3M) — dead after attr_match
    //     aliased later: ent partial [0, 3M)
    //   [4718592, +1MB)     scores
    //   [5767168, +4KB)     idxL/idxR
    //   [5771264, +48KB)    xcat
    //   [5820416, +96KB)    hsum
    //   [5918720, +1.5MB)   Lt (transposed L)         — dead after scores_kernel
    char* ws = (char*)d_ws;
    u16*   wsplit  = (u16*)ws;
    float* scores  = (float*)(ws + 4718592);
    int*   idxL    = (int*)(ws + 5767168);
    int*   idxR    = idxL + 512;
    float* xcat    = (float*)(ws + 5771264);
    float* hsum    = (float*)(ws + 5820416);
    float* Lt      = (float*)(ws + 5918720);
    float* lcmp    = (float*)ws;
    float* rcmp    = lcmp + (size_t)LTOK * DIM;
    float* partial = (float*)ws;

    wsplit_kernel<<<dim3(288), 256, 0, stream>>>(tWn, tWg, wsplit);

    ltrans_kernel<<<dim3(DIM / 32, LTOK / 32), 256, 0, stream>>>(Lg, Lt);

    scores_kernel<<<dim3(LTOK / 64, RTOK / 4), 256, 0, stream>>>(
        Lg, Rg, Lt, wsplit, tbn, tbg, tWl, scores);

    argmax_kernel<<<dim3(LTOK + RTOK), 64, 0, stream>>>(scores, idxL, idxR);

    build_cmp_kernel<<<dim3(LTOK + RTOK), 256, 0, stream>>>(
        Lg, Rg, idxL, idxR, lcmp, rcmp);

    attr_match_kernel<<<dim3(16), 256, 0, stream>>>(
        Lg, Rg, lcmp, rcmp, lensL, lensR, embL, embR, emptyR, xcat);

    ent_partial_kernel<<<dim3(EDIM / 1024, 32, 2), 256, 0, stream>>>(
        eWn, eWg, xcat, partial);

    ent_reduce_kernel<<<dim3(EDIM / 1024, 2), 256, 0, stream>>>(partial, hsum);

    finalize_kernel<<<dim3(1), 256, 0, stream>>>(
        hsum, xcat, ebn, ebg, eWl, ebl, out);
}

// Round 9
// 2071.184 us; speedup vs baseline: 1.2894x; 1.0137x over previous
//
#include <hip/hip_runtime.h>
#include <cmath>

#define NL 8
#define NR 8
#define DIM 768
#define LTOK 512
#define RTOK 512
#define EDIM 12288   // (NL+NR)*DIM
#define KST 32       // K per pipeline stage

typedef unsigned short u16;
typedef __bf16 bf16x8 __attribute__((ext_vector_type(8)));
typedef float  f32x16 __attribute__((ext_vector_type(16)));

#define WARR 589824          // 768*768 elements per split array
// frag-major layout for W (per array): idx(k,d) = ((k>>3)*768 + d)*8 + (k&7)

// RNE split of f32 into bf16 hi + bf16 lo (x ~= hi + lo; residual exact in f32)
__device__ __forceinline__ void splitbf(float c, u16& hi, u16& lo) {
    __bf16 h = (__bf16)c;
    __bf16 l = (__bf16)(c - (float)h);
    hi = __builtin_bit_cast(u16, h);
    lo = __builtin_bit_cast(u16, l);
}

__device__ __forceinline__ void gll16(const void* gsrc, void* lds) {
    __builtin_amdgcn_global_load_lds(
        (const __attribute__((address_space(1))) unsigned int*)gsrc,
        (__attribute__((address_space(3))) unsigned int*)lds, 16, 0, 0);
}

// ---------------------------------------------------------------------------
// Kernel 0: pre-split token-matching weights into bf16 hi/lo, frag-major.
// ---------------------------------------------------------------------------
__global__ __launch_bounds__(256) void wsplit_kernel(
    const float* __restrict__ Wn, const float* __restrict__ Wg, u16* __restrict__ out)
{
    const int gid = blockIdx.x * 256 + threadIdx.x;   // 768 d x 96 kg = 73728
    const int d  = gid % DIM;
    const int kg = gid / DIM;
    u16 hn[8], ln[8], hg[8], lg2[8];
#pragma unroll
    for (int e = 0; e < 8; ++e) {
        splitbf(Wn[(size_t)(kg * 8 + e) * DIM + d], hn[e], ln[e]);
        splitbf(Wg[(size_t)(kg * 8 + e) * DIM + d], hg[e], lg2[e]);
    }
    const size_t fo = ((size_t)kg * DIM + d) * 8;
    *(uint4*)&out[fo]            = *(uint4*)hn;
    *(uint4*)&out[WARR + fo]     = *(uint4*)ln;
    *(uint4*)&out[2 * WARR + fo] = *(uint4*)hg;
    *(uint4*)&out[3 * WARR + fo] = *(uint4*)lg2;
}

// ---------------------------------------------------------------------------
// Kernel 0b: transpose L into Lt[k][i]  (768 x 512) so lT staging is linear.
// ---------------------------------------------------------------------------
__global__ __launch_bounds__(256) void ltrans_kernel(
    const float* __restrict__ Lg, float* __restrict__ Lt)
{
    __shared__ float tile[32][33];
    const int tx  = threadIdx.x & 31;
    const int ty4 = threadIdx.x >> 5;          // 8 groups of 4 rows
    const int k0 = blockIdx.x * 32, i0 = blockIdx.y * 32;
#pragma unroll
    for (int rr = 0; rr < 4; ++rr) {
        int iy = ty4 * 4 + rr;
        tile[iy][tx] = Lg[(size_t)(i0 + iy) * DIM + k0 + tx];
    }
    __syncthreads();
#pragma unroll
    for (int rr = 0; rr < 4; ++rr) {
        int ky = ty4 * 4 + rr;
        Lt[(size_t)(k0 + ky) * LTOK + i0 + tx] = tile[tx][ky];
    }
}

// ---------------------------------------------------------------------------
// Kernel 1: token-matching scores via bf16x3 split MFMA (32x32x16).
// v6 = v5's counted-vmcnt pipeline, restructured to ONE 512-thread block per
// CU (8 waves = 8 j-columns, single barrier group). Removes the 2-block
// barrier anti-phasing; W/lT shared by 8 waves (per-wave VMEM issue halves).
// vmcnt(4) -> vmcnt(2) (1 lT gll + 2 W glls per wave per stage).
// Math/layouts identical to the absmax-0 kernels.
// ---------------------------------------------------------------------------
__global__ __launch_bounds__(512, 2) void scores_kernel(
    const float* __restrict__ Lg, const float* __restrict__ Rg,
    const float* __restrict__ Lt,
    const u16* __restrict__ wfrag,
    const float* __restrict__ bn, const float* __restrict__ bg,
    const float* __restrict__ Wl,
    float* __restrict__ scores)
{
    __shared__ u16   wLDS[3 * 8192];    // 48 KB: [buf][arr4][kg4][d64][e8]
    __shared__ float lLDS[2 * 2048];    // 16 KB: [buf][k32][i64] (transposed)
    __shared__ float rLDS[8 * 768];     // 24 KB: [j][k] full-K resident

    const int t    = threadIdx.x;
    const int lane = t & 63;
    const int wid  = t >> 6;            // 0..7 = j-column
    const int l31  = lane & 31;
    const int kh   = lane >> 5;
    const int i0   = blockIdx.x * 64;
    const int j0   = blockIdx.y * 8;
    const int j    = j0 + wid;

    const ptrdiff_t WSTEP = (ptrdiff_t)4 * DIM * 8;          // kgb += 4
    const ptrdiff_t WROLL = (ptrdiff_t)(64 - 92 * DIM) * 8;  // kgb 92->0, dg += 64

    // W sources (per-lane): chunk c = it*8+wid -> arr = c>>2, kg = c&3
    const u16* wp[2];
#pragma unroll
    for (int it = 0; it < 2; ++it) {
        const int c = it * 8 + wid;
        wp[it] = wfrag + (size_t)(c >> 2) * WARR + ((size_t)(c & 3) * DIM + lane) * 8;
    }

    // lT source (per-lane): thread t covers k_local = t>>4, i = (t&15)*4
    const float* apL = Lt + (size_t)(t >> 4) * LTOK + i0 + (t & 15) * 4;

    // ---- prologue: issue lT(0), W(0), rT, W(1); wait all but W(1) ----
    gll16(apL, lLDS + wid * 256);
#pragma unroll
    for (int it = 0; it < 2; ++it)
        gll16(wp[it], wLDS + (it * 8 + wid) * 512);
#pragma unroll
    for (int r = 0; r < 3; ++r)
        gll16(Rg + (size_t)j0 * DIM + (size_t)(r * 512 + t) * 4,
              rLDS + r * 2048 + wid * 256);
#pragma unroll
    for (int it = 0; it < 2; ++it)
        gll16(wp[it] + WSTEP, wLDS + 8192 + (it * 8 + wid) * 512);

    // advance to steady-state targets: wp -> stage 2, apL -> stage 1 (k=32)
#pragma unroll
    for (int it = 0; it < 2; ++it) wp[it] += 2 * WSTEP;
    apL += 16384;

    asm volatile("s_waitcnt vmcnt(2)" ::: "memory");
    __builtin_amdgcn_s_barrier();

    float sacc[2][16];
#pragma unroll
    for (int tile = 0; tile < 2; ++tile)
#pragma unroll
        for (int r = 0; r < 16; ++r) sacc[tile][r] = 0.f;

    f32x16 acc[2][2][2];                        // [tile][mat][nd]
#pragma unroll
    for (int tile = 0; tile < 2; ++tile)
#pragma unroll
        for (int mat = 0; mat < 2; ++mat)
#pragma unroll
            for (int nd = 0; nd < 2; ++nd)
#pragma unroll
                for (int r = 0; r < 16; ++r) acc[tile][mat][nd][r] = 0.f;

    int ksC = 0, k0C = 0, dg = 0, lRd = 0;
    const u16* wRd = wLDS;
    u16*       wWr = wLDS + 2 * 8192;
    const u16* const wEndc = wLDS + 3 * 8192;

#pragma unroll 1
    for (int s = 0; s < 288; ++s) {
        // one kk sub-phase: A-gen + 24 MFMAs (setprio-wrapped)
        auto phase = [&](int kk) {
            const float* rrow = rLDS + wid * 768 + k0C + kh * 8;
            float rv[8];
#pragma unroll
            for (int e = 0; e < 8; e += 2) {
                float2 p = *(const float2*)(rrow + kk * 16 + e);
                rv[e] = p.x; rv[e + 1] = p.y;
            }
            bf16x8 ah[2], al[2];
            const float* lb = lLDS + lRd * 2048 + kh * 512;
#pragma unroll
            for (int tile = 0; tile < 2; ++tile) {
                const float* lp = lb + kk * 1024 + tile * 32 + l31;
#pragma unroll
                for (int e = 0; e < 8; ++e) {
                    float c = fabsf(lp[e * 64] - rv[e]);
                    __bf16 h = (__bf16)c;
                    ah[tile][e] = h;
                    al[tile][e] = (__bf16)(c - (float)h);
                }
            }
            __builtin_amdgcn_s_setprio(1);
#pragma unroll
            for (int mat = 0; mat < 2; ++mat)
#pragma unroll
                for (int nd = 0; nd < 2; ++nd) {
                    const int base = (mat * 2) * 2048 + (kk * 2 + kh) * 512
                                   + (nd * 32 + l31) * 8;
                    bf16x8 whi = *(const bf16x8*)&wRd[base];
                    bf16x8 wlo = *(const bf16x8*)&wRd[base + 2048];
#pragma unroll
                    for (int tile = 0; tile < 2; ++tile) {
                        acc[tile][mat][nd] = __builtin_amdgcn_mfma_f32_32x32x16_bf16(
                            ah[tile], whi, acc[tile][mat][nd], 0, 0, 0);
                        acc[tile][mat][nd] = __builtin_amdgcn_mfma_f32_32x32x16_bf16(
                            al[tile], whi, acc[tile][mat][nd], 0, 0, 0);
                        acc[tile][mat][nd] = __builtin_amdgcn_mfma_f32_32x32x16_bf16(
                            ah[tile], wlo, acc[tile][mat][nd], 0, 0, 0);
                    }
                }
            __builtin_amdgcn_s_setprio(0);
        };

        // ---- issue lT(s+1), then compute kk=0 ----
        if (s < 287) {
            gll16(apL, lLDS + (lRd ^ 1) * 2048 + wid * 256);
            apL += (ksC == 22) ? (ptrdiff_t)-376832 : (ptrdiff_t)16384;
        }
        phase(0);

        // ---- issue W(s+2) under kk=0's MFMA shadow, then compute kk=1 ----
        if (s < 286) {
#pragma unroll
            for (int it = 0; it < 2; ++it)
                gll16(wp[it], wWr + (it * 8 + wid) * 512);
            const ptrdiff_t adv = (ksC == 21) ? WROLL : WSTEP;
#pragma unroll
            for (int it = 0; it < 2; ++it) wp[it] += adv;
        }
        phase(1);

        if (ksC == 23) {
            // sweep epilogue: nonlinearity + score accum for d in [dg,dg+64)
            // C layout (32x32): col(d) = lane&31, row(i) = (reg&3)+8*(reg>>2)+4*kh
#pragma unroll
            for (int nd = 0; nd < 2; ++nd) {
                const int dd = dg + nd * 32 + l31;
                const float bnv = bn[dd], bgv = bg[dd], wlv = Wl[dd];
                const float rvv = Rg[(size_t)j * DIM + dd];
#pragma unroll
                for (int tile = 0; tile < 2; ++tile)
#pragma unroll
                    for (int r = 0; r < 16; ++r) {
                        const int m = (r & 3) + 8 * (r >> 2) + 4 * kh;
                        const int i = i0 + tile * 32 + m;
                        float h  = fmaxf(acc[tile][0][nd][r] + bnv, 0.f);
                        float g  = 1.f / (1.f + __expf(-(acc[tile][1][nd][r] + bgv)));
                        float cc = fabsf(Lg[(size_t)i * DIM + dd] - rvv);
                        sacc[tile][r] = fmaf(wlv, fmaf(g, h - cc, cc), sacc[tile][r]);
                    }
            }
#pragma unroll
            for (int tile = 0; tile < 2; ++tile)
#pragma unroll
                for (int mat = 0; mat < 2; ++mat)
#pragma unroll
                    for (int nd = 0; nd < 2; ++nd)
#pragma unroll
                        for (int r = 0; r < 16; ++r) acc[tile][mat][nd][r] = 0.f;
        }

        // ---- counted-vmcnt barrier: keep W(s+2) in flight ----
        if (s == 286) { asm volatile("s_waitcnt vmcnt(0)" ::: "memory"); }
        else         { asm volatile("s_waitcnt vmcnt(2)" ::: "memory"); }
        __builtin_amdgcn_s_barrier();

        lRd ^= 1;
        wRd += 8192; if (wRd == wEndc) wRd = wLDS;
        wWr += 8192; if (wWr == (u16*)wEndc) wWr = wLDS;
        ++ksC; k0C += KST;
        if (ksC == 24) { ksC = 0; k0C = 0; dg += 64; }
    }

    // reduce sacc over the 32 lanes of each half (d direction), write scores
#pragma unroll
    for (int tile = 0; tile < 2; ++tile)
#pragma unroll
        for (int r = 0; r < 16; ++r) {
            float v = sacc[tile][r];
            v += __shfl_xor(v, 1);  v += __shfl_xor(v, 2);
            v += __shfl_xor(v, 4);  v += __shfl_xor(v, 8);
            v += __shfl_xor(v, 16);
            if (l31 == 0) {
                const int m = (r & 3) + 8 * (r >> 2) + 4 * kh;
                scores[(size_t)(i0 + tile * 32 + m) * RTOK + j] = v;
            }
        }
}

// ---------------------------------------------------------------------------
// Kernel 2: argmax per row (left) and per column (right); first-occurrence ties.
// ---------------------------------------------------------------------------
__global__ __launch_bounds__(64) void argmax_kernel(
    const float* __restrict__ scores, int* __restrict__ idxL, int* __restrict__ idxR)
{
    const int b = blockIdx.x;          // 0..511 rows, 512..1023 cols
    const int t = threadIdx.x;
    const bool isRow = (b < LTOK);
    const int  n = b & (LTOK - 1);

    float best = -INFINITY;
    int   bidx = 0x7fffffff;
    for (int s = t; s < 512; s += 64) {
        float v = isRow ? scores[n * RTOK + s] : scores[s * RTOK + n];
        if (v > best) { best = v; bidx = s; }
    }
#pragma unroll
    for (int off = 32; off; off >>= 1) {
        float ob = __shfl_down(best, off);
        int   oi = __shfl_down(bidx, off);
        if (ob > best || (ob == best && oi < bidx)) { best = ob; bidx = oi; }
    }
    if (t == 0) (isRow ? idxL : idxR)[n] = bidx;
}

// ---------------------------------------------------------------------------
// Kernel 3: gather chosen cmp rows.
// ---------------------------------------------------------------------------
__global__ __launch_bounds__(256) void build_cmp_kernel(
    const float* __restrict__ Lg, const float* __restrict__ Rg,
    const int* __restrict__ idxL, const int* __restrict__ idxR,
    float* __restrict__ lcmp, float* __restrict__ rcmp)
{
    const int b = blockIdx.x;
    const int t = threadIdx.x;
    if (b < LTOK) {
        const float* a = Lg + b * DIM;
        const float* c = Rg + idxL[b] * DIM;
        for (int d = t; d < DIM; d += 256) lcmp[b * DIM + d] = fabsf(a[d] - c[d]);
    } else {
        const int jj = b - LTOK;
        const float* a = Rg + jj * DIM;
        const float* c = Lg + idxR[jj] * DIM;
        for (int d = t; d < DIM; d += 256) rcmp[jj * DIM + d] = fabsf(a[d] - c[d]);
    }
}

// ---------------------------------------------------------------------------
// Kernel 4: attribute matching (ragged segment softmax + weighted cmp sum).
// ---------------------------------------------------------------------------
__global__ __launch_bounds__(256) void attr_match_kernel(
    const float* __restrict__ Lg, const float* __restrict__ Rg,
    const float* __restrict__ lcmp, const float* __restrict__ rcmp,
    const int* __restrict__ lensL, const int* __restrict__ lensR,
    const float* __restrict__ embL, const float* __restrict__ embR,
    const float* __restrict__ emptyRes,
    float* __restrict__ x)
{
    __shared__ float logits[512];
    __shared__ float red[256];

    const int b    = blockIdx.x;
    const int side = b >> 3;
    const int a    = b & 7;
    const int t    = threadIdx.x;

    const int*   lens = side ? lensR : lensL;
    const float* toks = side ? Rg   : Lg;
    const float* cmp  = side ? rcmp : lcmp;
    const float* femb = (side ? embR : embL) + a * DIM;
    float* outp = x + (side * 8 + a) * DIM;

    int start = 0;
    for (int q = 0; q < a; ++q) start += lens[q];
    const int len = lens[a];

    if (len == 0) {
        for (int d = t; d < DIM; d += 256) outp[d] = emptyRes[d];
        return;
    }

    for (int tok = t; tok < len; tok += 256) {
        const float* tr = toks + (start + tok) * DIM;
        float s = 0.f;
        for (int d = 0; d < DIM; ++d) s = fmaf(tr[d], femb[d], s);
        logits[tok] = s;
    }
    __syncthreads();

    float m = -INFINITY;
    for (int tok = t; tok < len; tok += 256) m = fmaxf(m, logits[tok]);
    red[t] = m; __syncthreads();
    for (int off = 128; off; off >>= 1) {
        if (t < off) red[t] = fmaxf(red[t], red[t + off]);
        __syncthreads();
    }
    m = red[0]; __syncthreads();

    float sum = 0.f;
    for (int tok = t; tok < len; tok += 256) {
        float e = expf(logits[tok] - m);
        logits[tok] = e;
        sum += e;
    }
    red[t] = sum; __syncthreads();
    for (int off = 128; off; off >>= 1) {
        if (t < off) red[t] += red[t + off];
        __syncthreads();
    }
    const float inv = 1.f / red[0];
    __syncthreads();

    for (int d = t; d < DIM; d += 256) {
        float accv = 0.f;
        for (int tok = 0; tok < len; ++tok)
            accv = fmaf(logits[tok] * inv, cmp[(start + tok) * DIM + d], accv);
        outp[d] = accv;
    }
}

// ---------------------------------------------------------------------------
// Kernel 5: entity highway matvec partials (split-K, deterministic).
// ---------------------------------------------------------------------------
__global__ __launch_bounds__(256) void ent_partial_kernel(
    const float* __restrict__ Wn, const float* __restrict__ Wg,
    const float* __restrict__ x, float* __restrict__ partial)
{
    __shared__ float xs[384];
    const int ob   = blockIdx.x;   // 12
    const int slab = blockIdx.y;   // 32
    const int mat  = blockIdx.z;   // 2
    const float* W = mat ? Wg : Wn;
    const int t  = threadIdx.x;
    const int o0 = ob * 1024 + t * 4;
    const int in0 = slab * 384;

    for (int i = t; i < 384; i += 256) xs[i] = x[in0 + i];
    __syncthreads();

    float4 acc = {0.f, 0.f, 0.f, 0.f};
    for (int in = 0; in < 384; ++in) {
        const float  xv = xs[in];
        const float4 w  = *(const float4*)(W + (size_t)(in0 + in) * EDIM + o0);
        acc.x = fmaf(xv, w.x, acc.x);
        acc.y = fmaf(xv, w.y, acc.y);
        acc.z = fmaf(xv, w.z, acc.z);
        acc.w = fmaf(xv, w.w, acc.w);
    }
    *(float4*)(partial + ((size_t)mat * 32 + slab) * EDIM + o0) = acc;
}

// ---------------------------------------------------------------------------
// Kernel 6: reduce the 32 split-K partials.
// ---------------------------------------------------------------------------
__global__ __launch_bounds__(256) void ent_reduce_kernel(
    const float* __restrict__ partial, float* __restrict__ hsum)
{
    const int mat = blockIdx.y;
    const int o   = blockIdx.x * 1024 + threadIdx.x * 4;
    float4 acc = {0.f, 0.f, 0.f, 0.f};
    for (int s = 0; s < 32; ++s) {
        const float4 p = *(const float4*)(partial + ((size_t)mat * 32 + s) * EDIM + o);
        acc.x += p.x; acc.y += p.y; acc.z += p.z; acc.w += p.w;
    }
    *(float4*)(hsum + (size_t)mat * EDIM + o) = acc;
}

// ---------------------------------------------------------------------------
// Kernel 7: entity highway epilogue + final linear + softmax.
// ---------------------------------------------------------------------------
__global__ __launch_bounds__(256) void finalize_kernel(
    const float* __restrict__ hsum, const float* __restrict__ x,
    const float* __restrict__ bn, const float* __restrict__ bg,
    const float* __restrict__ Wl2, const float* __restrict__ bl2,
    float* __restrict__ out)
{
    __shared__ float r0[256], r1[256];
    const int t = threadIdx.x;
    float l0 = 0.f, l1 = 0.f;
    for (int d = t; d < EDIM; d += 256) {
        float h  = fmaxf(hsum[d] + bn[d], 0.f);
        float gv = 1.f / (1.f + expf(-(hsum[EDIM + d] + bg[d])));
        float hw = gv * h + (1.f - gv) * x[d];
        l0 = fmaf(hw, Wl2[d * 2 + 0], l0);
        l1 = fmaf(hw, Wl2[d * 2 + 1], l1);
    }
    r0[t] = l0; r1[t] = l1; __syncthreads();
    for (int off = 128; off; off >>= 1) {
        if (t < off) { r0[t] += r0[t + off]; r1[t] += r1[t + off]; }
        __syncthreads();
    }
    if (t == 0) {
        float a = r0[0] + bl2[0];
        float b = r1[0] + bl2[1];
        float m  = fmaxf(a, b);
        float ea = expf(a - m), eb = expf(b - m);
        float inv = 1.f / (ea + eb);
        out[0] = ea * inv;
        out[1] = eb * inv;
    }
}

// ---------------------------------------------------------------------------
extern "C" void kernel_launch(void* const* d_in, const int* in_sizes, int n_in,
                              void* d_out, int out_size, void* d_ws, size_t ws_size,
                              hipStream_t stream)
{
    const float* Lg     = (const float*)d_in[0];
    const float* Rg     = (const float*)d_in[1];
    const int*   lensL  = (const int*)  d_in[2];
    const int*   lensR  = (const int*)  d_in[3];
    const float* tWn    = (const float*)d_in[4];
    const float* tbn    = (const float*)d_in[5];
    const float* tWg    = (const float*)d_in[6];
    const float* tbg    = (const float*)d_in[7];
    const float* tWl    = (const float*)d_in[8];
    // d_in[9] = lin_tok_b : constant score shift, irrelevant to argmax
    const float* embL   = (const float*)d_in[10];
    const float* embR   = (const float*)d_in[11];
    const float* eWn    = (const float*)d_in[12];
    const float* ebn    = (const float*)d_in[13];
    const float* eWg    = (const float*)d_in[14];
    const float* ebg    = (const float*)d_in[15];
    const float* eWl    = (const float*)d_in[16];
    const float* ebl    = (const float*)d_in[17];
    const float* emptyR = (const float*)d_in[18];
    float* out = (float*)d_out;

    // workspace layout (bytes):
    //   [0, 4718592)        wsplit (4 x 768^2 bf16)   — dead after scores_kernel
    //     aliased later: lcmp [0,1.5M) + rcmp [1.5M,3M) — dead after attr_match
    //     aliased later: ent partial [0, 3M)
    //   [4718592, +1MB)     scores
    //   [5767168, +4KB)     idxL/idxR
    //   [5771264, +48KB)    xcat
    //   [5820416, +96KB)    hsum
    //   [5918720, +1.5MB)   Lt (transposed L)         — dead after scores_kernel
    char* ws = (char*)d_ws;
    u16*   wsplit  = (u16*)ws;
    float* scores  = (float*)(ws + 4718592);
    int*   idxL    = (int*)(ws + 5767168);
    int*   idxR    = idxL + 512;
    float* xcat    = (float*)(ws + 5771264);
    float* hsum    = (float*)(ws + 5820416);
    float* Lt      = (float*)(ws + 5918720);
    float* lcmp    = (float*)ws;
    float* rcmp    = lcmp + (size_t)LTOK * DIM;
    float* partial = (float*)ws;

    wsplit_kernel<<<dim3(288), 256, 0, stream>>>(tWn, tWg, wsplit);

    ltrans_kernel<<<dim3(DIM / 32, LTOK / 32), 256, 0, stream>>>(Lg, Lt);

    scores_kernel<<<dim3(LTOK / 64, RTOK / 8), 512, 0, stream>>>(
        Lg, Rg, Lt, wsplit, tbn, tbg, tWl, scores);

    argmax_kernel<<<dim3(LTOK + RTOK), 64, 0, stream>>>(scores, idxL, idxR);

    build_cmp_kernel<<<dim3(LTOK + RTOK), 256, 0, stream>>>(
        Lg, Rg, idxL, idxR, lcmp, rcmp);

    attr_match_kernel<<<dim3(16), 256, 0, stream>>>(
        Lg, Rg, lcmp, rcmp, lensL, lensR, embL, embR, emptyR, xcat);

    ent_partial_kernel<<<dim3(EDIM / 1024, 32, 2), 256, 0, stream>>>(
        eWn, eWg, xcat, partial);

    ent_reduce_kernel<<<dim3(EDIM / 1024, 2), 256, 0, stream>>>(partial, hsum);

    finalize_kernel<<<dim3(1), 256, 0, stream>>>(
        hsum, xcat, ebn, ebg, eWl, ebl, out);
}